// Round 7
// baseline (170.035 us; speedup 1.0000x reference)
//
#include <hip/hip_runtime.h>

// TriangleAttentionStartingNode — MI355X gfx950. f32 global I/O, bf16 MFMA compute.
//
// R11: head-split residency round. Ledger: R8 (2 blk/CU, proj x2 dup) 51.5us;
// R9 (4 blk/CU, x4 dup) 61.5us; R10 (1 blk/CU, x1 dup) 54us + conflicts up
// + barrier drains with nothing to overlap. Unexplored corner: work x1 AND
// 2 blk/CU. Split HEADS across blocks, not queries: grid (2,256), each
// 512-thread block owns a head-pair for its row -> projection/QG/attention
// computed exactly once chip-wide (only LN duplicated x2). Cross-block sum
// via f32 global atomicAdd onto memset-zeroed out (2 contributors/address,
// f32 add commutes -> deterministic); bo folded into hp==0 acc init.
// Barriers 9 -> 5. R10 staging layouts kept (single-b128 fragments).
//
// Kept: v_perm round-half-up bf16 packing; softmax scale*log2e folded into
// Q; no exp clamp (post-LN scores O(1)); Wb unused (softmax shift
// invariance); tree-reduced l; plain __launch_bounds__ (2nd arg spills).

typedef unsigned short u16;
typedef unsigned int   u32;
typedef __bf16 bf16x8 __attribute__((ext_vector_type(8)));
typedef float  f32x4  __attribute__((ext_vector_type(4)));

union U8 { bf16x8 b; u32 u[4]; };

// round-half-up f32->bf16 pair pack: 2 adds + 1 v_perm
__device__ __forceinline__ u32 pk(float a, float b) {
  const u32 au = __float_as_uint(a) + 0x8000u;
  const u32 bu = __float_as_uint(b) + 0x8000u;
  return __builtin_amdgcn_perm(bu, au, 0x07060302u);  // {b.hi16, a.hi16}
}
__device__ __forceinline__ f32x4 mfma16(bf16x8 a, bf16x8 b, f32x4 c) {
  return __builtin_amdgcn_mfma_f32_16x16x32_bf16(a, b, c, 0, 0, 0);
}

#define LDZ 40    // 80 B rows, 16B-aligned
#define LDK 40    // 80 B rows, 16B-aligned (fragment = 16 contiguous ch at quad*8)
#define LDV 264   // 528 B rows, 16B-aligned (key dim permuted per 32-block)

__global__ __launch_bounds__(512) void tri_attn_fused(
    const float* __restrict__ z,  const float* __restrict__ ln_g, const float* __restrict__ ln_b,
    const float* __restrict__ Wq, const float* __restrict__ Wk,   const float* __restrict__ Wv,
    const float* __restrict__ Wg, const float* __restrict__ bg,
    const float* __restrict__ Wo, const float* __restrict__ bo,   float* __restrict__ out)
{
  __shared__ u16 sZ [256][LDZ];   // zn[pos][ch]                 20480 B
  __shared__ u16 sK [256][LDK];   // K[key][frag-ordered ch]     20480 B
  __shared__ u16 sVt[32][LDV];    // V^T[ch][perm key]           16896 B

  const int hp   = blockIdx.x;    // head pair: heads {hp*2, hp*2+1}
  const int i    = blockIdx.y;
  const int tid  = threadIdx.x;
  const int wave = tid >> 6, lane = tid & 63, quad = lane >> 4, col = lane & 15;
  const f32x4 z4 = {0.f, 0.f, 0.f, 0.f};

  // ---------------- phase 0: LayerNorm (2 threads per position) ----------------
  {
    const int pos = tid >> 1, hf = tid & 1;
    const float* zr = z + ((((i << 8) + pos) << 5) + hf*16);
    float x[16];
#pragma unroll
    for (int e = 0; e < 4; e++) {
      const float4 v = *(const float4*)(zr + e*4);
      x[4*e] = v.x; x[4*e+1] = v.y; x[4*e+2] = v.z; x[4*e+3] = v.w;
    }
    float s = 0.f;
#pragma unroll
    for (int c = 0; c < 16; c++) s += x[c];
    const float mu = (s + __shfl_xor(s, 1)) * (1.f / 32.f);
    float d2 = 0.f;
#pragma unroll
    for (int c = 0; c < 16; c++) { float d = x[c] - mu; d2 += d * d; }
    const float var = (d2 + __shfl_xor(d2, 1)) * (1.f / 32.f);
    const float rstd = rsqrtf(var + 1e-5f);
    u32* dst = (u32*)&sZ[pos][hf*16];
#pragma unroll
    for (int e = 0; e < 8; e++) {
      const int c = hf*16 + 2*e;
      const float za = (x[2*e]   - mu) * rstd * ln_g[c]   + ln_b[c];
      const float zb = (x[2*e+1] - mu) * rstd * ln_g[c+1] + ln_b[c+1];
      dst[e] = pk(za, zb);
    }
  }
  __syncthreads();

  // fp32 out accumulators; hp==0 block carries bo (other block adds 0)
  f32x4 acc[2][2];
  {
    const float w = (hp == 0) ? 1.f : 0.f;
#pragma unroll
    for (int r = 0; r < 4; r++) {
      acc[0][0][r] = acc[1][0][r] = bo[quad*4 + r] * w;
      acc[0][1][r] = acc[1][1][r] = bo[16 + quad*4 + r] * w;
    }
  }
  const float k2e = 0.17677669529663687f * 1.44269504089f;   // (1/sqrt32)*log2(e)

  for (int hh = 0; hh < 2; ++hh) {
    const int h = hp*2 + hh;
    // weight fragments (f32 -> bf16 pack), loaded once per head (L1/L2-hot)
    auto ldw = [&](const float* W, int cb) -> U8 {
      const float* p = W + h*1024 + (cb*16 + col)*32 + quad*8;
      const float4 a = *(const float4*)(p);
      const float4 b = *(const float4*)(p + 4);
      U8 t;
      t.u[0] = pk(a.x, a.y); t.u[1] = pk(a.z, a.w);
      t.u[2] = pk(b.x, b.y); t.u[3] = pk(b.z, b.w);
      return t;
    };

    // -------- Q/G pre-phase: 2 q-tiles/wave (8 waves cover all 256 q) --------
    U8    QB[2];       // Q (pre-scaled) permuted-k B-frags
    float G[2][8];     // gates, O^T C-layout
    {
      const U8 WqF0 = ldw(Wq,0), WqF1 = ldw(Wq,1);
      const U8 WgF0 = ldw(Wg,0), WgF1 = ldw(Wg,1);
      float bgl[8];
#pragma unroll
      for (int r = 0; r < 4; r++) {
        bgl[r]     = bg[h*32 + quad*4 + r];
        bgl[4 + r] = bg[h*32 + 16 + quad*4 + r];
      }
#pragma unroll
      for (int qt = 0; qt < 2; qt++) {
        const int row = (wave*2 + qt)*16 + col;
        U8 ZA;
        {
          const uint4 v = *(const uint4*)&sZ[row][quad*8];
          ZA.u[0] = v.x; ZA.u[1] = v.y; ZA.u[2] = v.z; ZA.u[3] = v.w;
        }
        const f32x4 q0 = mfma16(WqF0.b, ZA.b, z4);
        const f32x4 q1 = mfma16(WqF1.b, ZA.b, z4);
        const f32x4 g0 = mfma16(WgF0.b, ZA.b, z4);
        const f32x4 g1 = mfma16(WgF1.b, ZA.b, z4);
        QB[qt].u[0] = pk(q0[0]*k2e, q0[1]*k2e); QB[qt].u[1] = pk(q0[2]*k2e, q0[3]*k2e);
        QB[qt].u[2] = pk(q1[0]*k2e, q1[1]*k2e); QB[qt].u[3] = pk(q1[2]*k2e, q1[3]*k2e);
#pragma unroll
        for (int r = 0; r < 4; r++) {
          G[qt][r]     = 1.f / (1.f + __expf(-(g0[r] + bgl[r])));
          G[qt][4 + r] = 1.f / (1.f + __expf(-(g1[r] + bgl[4 + r])));
        }
      }
    }

    // -------- projection: all 256 keys once (8 waves x 2 tiles of 16) --------
    const U8 WkF0 = ldw(Wk,0), WkF1 = ldw(Wk,1);
    const U8 WvF0 = ldw(Wv,0), WvF1 = ldw(Wv,1);
#pragma unroll
    for (int pp = 0; pp < 2; pp++) {
      const int tile = pp*8 + wave;          // 0..15
      const int key  = tile*16 + col;        // this lane's key
      U8 ZA;
      {
        const uint4 v = *(const uint4*)&sZ[key][quad*8];
        ZA.u[0] = v.x; ZA.u[1] = v.y; ZA.u[2] = v.z; ZA.u[3] = v.w;
      }
      // K^T (C-layout: ch=quad*4+reg, key=col), V (key=quad*4+reg, ch=col)
      const f32x4 k0 = mfma16(WkF0.b, ZA.b, z4);
      const f32x4 k1 = mfma16(WkF1.b, ZA.b, z4);
      const f32x4 v0 = mfma16(ZA.b, WvF0.b, z4);
      const f32x4 v1 = mfma16(ZA.b, WvF1.b, z4);
      // K: one b128 store, fragment-ordered 16 channels at [key][quad*8]
      *(uint4*)&sK[key][quad*8] =
          make_uint4(pk(k0[0],k0[1]), pk(k0[2],k0[3]), pk(k1[0],k1[1]), pk(k1[2],k1[3]));
      // V^T: permuted key slots within each 32-block (k0-3,k16-19,k4-7,..)
      const int g  = tile & 1;
      const int sb = (tile >> 1)*32 + quad*8 + g*4;
      *(uint2*)&sVt[col][sb]      = make_uint2(pk(v0[0],v0[1]), pk(v0[2],v0[3]));
      *(uint2*)&sVt[16 + col][sb] = make_uint2(pk(v1[0],v1[1]), pk(v1[2],v1[3]));
    }
    __syncthreads();

    // -------- attention: kb outer (fragments shared by both q-tiles) --------
    float l[2]    = {0.f, 0.f};
    f32x4 O[2][2] = {{z4, z4}, {z4, z4}};   // O^T per qt: ch=quad*4+r (+16), q=col
#pragma unroll
    for (int kb = 0; kb < 256; kb += 32) {
      U8 KF0, KF1, VF0, VF1;   // one ds_read_b128 each
      {
        const uint4 a = *(const uint4*)&sK[kb + col][quad*8];
        KF0.u[0] = a.x; KF0.u[1] = a.y; KF0.u[2] = a.z; KF0.u[3] = a.w;
        const uint4 b = *(const uint4*)&sK[kb + 16 + col][quad*8];
        KF1.u[0] = b.x; KF1.u[1] = b.y; KF1.u[2] = b.z; KF1.u[3] = b.w;
        const uint4 c = *(const uint4*)&sVt[col][kb + quad*8];
        VF0.u[0] = c.x; VF0.u[1] = c.y; VF0.u[2] = c.z; VF0.u[3] = c.w;
        const uint4 d = *(const uint4*)&sVt[16 + col][kb + quad*8];
        VF1.u[0] = d.x; VF1.u[1] = d.y; VF1.u[2] = d.z; VF1.u[3] = d.w;
      }
#pragma unroll
      for (int qt = 0; qt < 2; qt++) {
        const f32x4 S0 = mfma16(KF0.b, QB[qt].b, z4);   // keys kb+quad*4+r
        const f32x4 S1 = mfma16(KF1.b, QB[qt].b, z4);   // keys kb+16+quad*4+r
        float ps[8];
#pragma unroll
        for (int r = 0; r < 4; r++) {
          ps[r]     = exp2f(S0[r]);     // scale pre-folded into Q; no clamp needed
          ps[4 + r] = exp2f(S1[r]);
        }
        l[qt] += ((ps[0]+ps[1]) + (ps[2]+ps[3])) + ((ps[4]+ps[5]) + (ps[6]+ps[7]));
        U8 PB;
        PB.u[0] = pk(ps[0],ps[1]); PB.u[1] = pk(ps[2],ps[3]);
        PB.u[2] = pk(ps[4],ps[5]); PB.u[3] = pk(ps[6],ps[7]);
        O[qt][0] = mfma16(VF0.b, PB.b, O[qt][0]);
        O[qt][1] = mfma16(VF1.b, PB.b, O[qt][1]);
      }
    }
    __syncthreads();   // protect sK/sVt before next head overwrites

    // -------- epilogue: normalize, gate, fused out-projection --------
    U8 WoA0, WoA1;   // Wo A-frags with matching k-permutation (qt-invariant)
    {
      const float4 a = *(const float4*)(Wo + col*128 + h*32 + quad*4);
      const float4 b = *(const float4*)(Wo + col*128 + h*32 + 16 + quad*4);
      WoA0.u[0] = pk(a.x,a.y); WoA0.u[1] = pk(a.z,a.w);
      WoA0.u[2] = pk(b.x,b.y); WoA0.u[3] = pk(b.z,b.w);
      const float4 c = *(const float4*)(Wo + (16 + col)*128 + h*32 + quad*4);
      const float4 d = *(const float4*)(Wo + (16 + col)*128 + h*32 + 16 + quad*4);
      WoA1.u[0] = pk(c.x,c.y); WoA1.u[1] = pk(c.z,c.w);
      WoA1.u[2] = pk(d.x,d.y); WoA1.u[3] = pk(d.z,d.w);
    }
#pragma unroll
    for (int qt = 0; qt < 2; qt++) {
      float lv = l[qt];
      lv += __shfl_xor(lv, 16);   // reduce over quads (keys spread reg-dim x quad)
      lv += __shfl_xor(lv, 32);
      const float inv = 1.f / lv;
      float og[8];
#pragma unroll
      for (int r = 0; r < 4; r++) {
        og[r]     = O[qt][0][r] * inv * G[qt][r];
        og[4 + r] = O[qt][1][r] * inv * G[qt][4 + r];
      }
      U8 OB;   // gated O^T as permuted-k B-frag (k-permutation matches WoA)
      OB.u[0] = pk(og[0],og[1]); OB.u[1] = pk(og[2],og[3]);
      OB.u[2] = pk(og[4],og[5]); OB.u[3] = pk(og[6],og[7]);
      acc[qt][0] = mfma16(WoA0.b, OB.b, acc[qt][0]);   // couts 0..15
      acc[qt][1] = mfma16(WoA1.b, OB.b, acc[qt][1]);   // couts 16..31
    }
  }

  // ---- epilogue: atomic cross-block sum (out pre-zeroed; bo in hp0's acc) ----
#pragma unroll
  for (int qt = 0; qt < 2; qt++) {
    const int pos = (i << 8) + (wave*2 + qt)*16 + col;
    float* op = out + pos*32;
#pragma unroll
    for (int r = 0; r < 4; r++) {
      atomicAdd(op + quad*4 + r,      acc[qt][0][r]);
      atomicAdd(op + 16 + quad*4 + r, acc[qt][1][r]);
    }
  }
}

extern "C" void kernel_launch(void* const* d_in, const int* in_sizes, int n_in,
                              void* d_out, int out_size, void* d_ws, size_t ws_size,
                              hipStream_t stream)
{
  const float* z    = (const float*)d_in[0];
  const float* ln_g = (const float*)d_in[1];
  const float* ln_b = (const float*)d_in[2];
  const float* Wq   = (const float*)d_in[3];
  const float* Wk   = (const float*)d_in[4];
  const float* Wv   = (const float*)d_in[5];
  // d_in[6] = Wb: softmax shift invariance -> exactly cancels, unused.
  const float* Wg   = (const float*)d_in[7];
  const float* bg   = (const float*)d_in[8];
  const float* Wo   = (const float*)d_in[9];
  const float* bo   = (const float*)d_in[10];

  hipMemsetAsync(d_out, 0, out_size, stream);   // atomic accumulation target
  tri_attn_fused<<<dim3(2, 256), 512, 0, stream>>>(z, ln_g, ln_b, Wq, Wk, Wv, Wg, bg, Wo, bo,
                                                   (float*)d_out);
}

// Round 8
// 112.010 us; speedup vs baseline: 1.5180x; 1.5180x over previous
//
#include <hip/hip_runtime.h>

// TriangleAttentionStartingNode — MI355X gfx950. f32 global I/O, bf16 MFMA compute.
//
// R12: transcendental-builtin round. Base = R8 verbatim (best clean kernel,
// 51.5us/dispatch). R9's occupancy A/B pinned VALUBusy at ~55% independent
// of residency -> VALU-issue-bound; static count of source VALU (~3.5K/wave)
// explains only ~1/5 of measured VALU-busy cycles. The gap: harness compiles
// -O3 WITHOUT -ffast-math, so libm exp2f -> __ocml_exp2_f32 (v_exp_f32 +
// denormal fixup, ~7 VALU each x 512 calls/thread), sigmoid's 1/(1+e^-x) ->
// full-precision div sequence (~10 instrs x 64/thread), plus rsqrtf/1/l.
// Single change: raw HW builtins — __builtin_amdgcn_exp2f (1 instr; scores
// O(1), denormal path irrelevant), sigmoid = v_rcp(1+v_exp(-x*log2e)),
// 1/l = v_rcp, LN rstd = v_rsq. rcp/rsq are <=1ulp f32 — noise vs the
// 3.9e-3 bf16 tolerance. (R11's global-atomic head-split: 97us, closed.)
//
// Kept from R8: grid (2,256), 256 thr; split-K staging (two 128-key halves
// per head; LDS 38.1 KB); plain __launch_bounds__(256) (2nd arg spills,
// R5/R6); v_perm round-half-up bf16 packing; softmax scale*log2e folded
// into Q; Wb unused (softmax shift invariance); tree-reduced l.

typedef unsigned short u16;
typedef unsigned int   u32;
typedef __bf16 bf16x8 __attribute__((ext_vector_type(8)));
typedef float  f32x4  __attribute__((ext_vector_type(4)));

union U8 { bf16x8 b; u32 u[4]; };

// round-half-up f32->bf16 pair pack: 2 adds + 1 v_perm
__device__ __forceinline__ u32 pk(float a, float b) {
  const u32 au = __float_as_uint(a) + 0x8000u;
  const u32 bu = __float_as_uint(b) + 0x8000u;
  return __builtin_amdgcn_perm(bu, au, 0x07060302u);  // {b.hi16, a.hi16}
}
__device__ __forceinline__ f32x4 mfma16(bf16x8 a, bf16x8 b, f32x4 c) {
  return __builtin_amdgcn_mfma_f32_16x16x32_bf16(a, b, c, 0, 0, 0);
}
// raw v_exp_f32 (no libm denormal fixup)
__device__ __forceinline__ float ex2(float x) { return __builtin_amdgcn_exp2f(x); }
// sigmoid via v_exp + v_rcp (1 ulp)
__device__ __forceinline__ float sigm(float x) {
  return __builtin_amdgcn_rcpf(1.f + __builtin_amdgcn_exp2f(-1.44269504089f * x));
}

#define LDZ 40    // 80 B rows (16B-aligned uint4 reads)
#define LDK 36    // 72 B rows
#define LDV 132   // 264 B rows

__global__ __launch_bounds__(256) void tri_attn_fused(
    const float* __restrict__ z,  const float* __restrict__ ln_g, const float* __restrict__ ln_b,
    const float* __restrict__ Wq, const float* __restrict__ Wk,   const float* __restrict__ Wv,
    const float* __restrict__ Wg, const float* __restrict__ bg,
    const float* __restrict__ Wo, const float* __restrict__ bo,   float* __restrict__ out)
{
  __shared__ u16 sZ [256][LDZ];   // zn[pos][ch]   bf16               20480 B
  __shared__ u16 sK [128][LDK];   // K[key%128][ch] bf16 (per half)    9216 B
  __shared__ u16 sVt[32][LDV];    // V^T[ch][key%128] bf16 (per half)  8448 B

  const int qhalf = blockIdx.x;
  const int i     = blockIdx.y;
  const int tid   = threadIdx.x;
  const int wave  = tid >> 6, lane = tid & 63, quad = lane >> 4, col = lane & 15;
  const f32x4 z4  = {0.f, 0.f, 0.f, 0.f};

  // ---------------- phase 0: LayerNorm (one thread per position) ----------------
  {
    const float* zr = z + (((i << 8) + tid) << 5);
    float x[32];
#pragma unroll
    for (int e = 0; e < 8; e++) {
      const float4 v = *(const float4*)(zr + e*4);
      x[4*e] = v.x; x[4*e+1] = v.y; x[4*e+2] = v.z; x[4*e+3] = v.w;
    }
    float mu = 0.f;
#pragma unroll
    for (int c = 0; c < 32; c++) mu += x[c];
    mu *= (1.f / 32.f);
    float s2 = 0.f;
#pragma unroll
    for (int c = 0; c < 32; c++) { float d = x[c] - mu; s2 += d * d; }
    const float rstd = __builtin_amdgcn_rsqf(s2 * (1.f / 32.f) + 1e-5f);
    u32* dst = (u32*)&sZ[tid][0];
#pragma unroll
    for (int e = 0; e < 16; e++) {
      const float za = (x[2*e]   - mu) * rstd * ln_g[2*e]   + ln_b[2*e];
      const float zb = (x[2*e+1] - mu) * rstd * ln_g[2*e+1] + ln_b[2*e+1];
      dst[e] = pk(za, zb);
    }
  }
  __syncthreads();

  f32x4 acc[2][2] = {{z4, z4}, {z4, z4}};   // fp32 out accumulators (across heads)
  const float k2e = 0.17677669529663687f * 1.44269504089f;   // (1/sqrt32)*log2(e)

  for (int h = 0; h < 4; ++h) {
    // weight fragments (f32 -> bf16 pack), loaded once per head (L1/L2-hot)
    auto ldw = [&](const float* W, int cb) -> U8 {
      const float* p = W + h*1024 + (cb*16 + col)*32 + quad*8;
      const float4 a = *(const float4*)(p);
      const float4 b = *(const float4*)(p + 4);
      U8 t;
      t.u[0] = pk(a.x, a.y); t.u[1] = pk(a.z, a.w);
      t.u[2] = pk(b.x, b.y); t.u[3] = pk(b.z, b.w);
      return t;
    };

    // -------- Q/G pre-phase: this block's 128 queries (2 tiles/wave) --------
    U8    QB[2];        // Q (pre-scaled) permuted-k B-frags
    float G[2][8];      // gates, O^T C-layout
    {
      const U8 WqF0 = ldw(Wq,0), WqF1 = ldw(Wq,1);
      const U8 WgF0 = ldw(Wg,0), WgF1 = ldw(Wg,1);
      float bgl[8];
#pragma unroll
      for (int r = 0; r < 4; r++) {
        bgl[r]     = bg[h*32 + quad*4 + r];
        bgl[4 + r] = bg[h*32 + 16 + quad*4 + r];
      }
#pragma unroll
      for (int p2 = 0; p2 < 2; p2++) {
        const int row = qhalf*128 + (p2*4 + wave)*16 + col;
        U8 ZA;
        {
          const uint4 v = *(const uint4*)&sZ[row][quad*8];
          ZA.u[0] = v.x; ZA.u[1] = v.y; ZA.u[2] = v.z; ZA.u[3] = v.w;
        }
        const f32x4 q0 = mfma16(WqF0.b, ZA.b, z4);
        const f32x4 q1 = mfma16(WqF1.b, ZA.b, z4);
        const f32x4 g0 = mfma16(WgF0.b, ZA.b, z4);
        const f32x4 g1 = mfma16(WgF1.b, ZA.b, z4);
        QB[p2].u[0] = pk(q0[0]*k2e, q0[1]*k2e); QB[p2].u[1] = pk(q0[2]*k2e, q0[3]*k2e);
        QB[p2].u[2] = pk(q1[0]*k2e, q1[1]*k2e); QB[p2].u[3] = pk(q1[2]*k2e, q1[3]*k2e);
#pragma unroll
        for (int r = 0; r < 4; r++) {
          G[p2][r]     = sigm(g0[r] + bgl[r]);
          G[p2][4 + r] = sigm(g1[r] + bgl[4 + r]);
        }
      }
    }

    const U8 WkF0 = ldw(Wk,0), WkF1 = ldw(Wk,1);
    const U8 WvF0 = ldw(Wv,0), WvF1 = ldw(Wv,1);

    float l[2]     = {0.f, 0.f};
    f32x4 O[2][2]  = {{z4, z4}, {z4, z4}};   // O^T per p2: ch=quad*4+r (+16), q=col

    // -------- two 128-key halves: project -> sync -> attend -> sync --------
#pragma unroll
    for (int m = 0; m < 2; m++) {
      // projection of keys m*128 .. m*128+127 (4 waves x 2 tiles of 16)
#pragma unroll
      for (int pp = 0; pp < 2; pp++) {
        const int lbase = (pp*4 + wave) * 16;        // local key base (0..112)
        const int grow  = m*128 + lbase + col;       // global position
        U8 ZA;
        {
          const uint4 v = *(const uint4*)&sZ[grow][quad*8];
          ZA.u[0] = v.x; ZA.u[1] = v.y; ZA.u[2] = v.z; ZA.u[3] = v.w;
        }
        // K^T (C-layout: ch=quad*4+reg, key=col), V (key=quad*4+reg, ch=col)
        const f32x4 k0 = mfma16(WkF0.b, ZA.b, z4);
        const f32x4 k1 = mfma16(WkF1.b, ZA.b, z4);
        const f32x4 v0 = mfma16(ZA.b, WvF0.b, z4);
        const f32x4 v1 = mfma16(ZA.b, WvF1.b, z4);
        *(uint2*)&sK[lbase + col][quad*4]        = make_uint2(pk(k0[0],k0[1]), pk(k0[2],k0[3]));
        *(uint2*)&sK[lbase + col][16 + quad*4]   = make_uint2(pk(k1[0],k1[1]), pk(k1[2],k1[3]));
        *(uint2*)&sVt[col][lbase + quad*4]       = make_uint2(pk(v0[0],v0[1]), pk(v0[2],v0[3]));
        *(uint2*)&sVt[16 + col][lbase + quad*4]  = make_uint2(pk(v1[0],v1[1]), pk(v1[2],v1[3]));
      }
      __syncthreads();

      // attention over this half's 128 keys, both q-tiles
#pragma unroll
      for (int p2 = 0; p2 < 2; p2++) {
#pragma unroll
        for (int kb = 0; kb < 128; kb += 32) {
          U8 KF0, KF1;
          {
            const uint2 a = *(const uint2*)&sK[kb + col][quad*4];
            const uint2 b = *(const uint2*)&sK[kb + col][16 + quad*4];
            KF0.u[0] = a.x; KF0.u[1] = a.y; KF0.u[2] = b.x; KF0.u[3] = b.y;
            const uint2 c = *(const uint2*)&sK[kb + 16 + col][quad*4];
            const uint2 d = *(const uint2*)&sK[kb + 16 + col][16 + quad*4];
            KF1.u[0] = c.x; KF1.u[1] = c.y; KF1.u[2] = d.x; KF1.u[3] = d.y;
          }
          const f32x4 S0 = mfma16(KF0.b, QB[p2].b, z4);   // keys kb+quad*4+r
          const f32x4 S1 = mfma16(KF1.b, QB[p2].b, z4);   // keys kb+16+quad*4+r
          float ps[8];
#pragma unroll
          for (int r = 0; r < 4; r++) {
            ps[r]     = ex2(S0[r]);     // scale pre-folded into Q; raw v_exp_f32
            ps[4 + r] = ex2(S1[r]);
          }
          l[p2] += ((ps[0]+ps[1]) + (ps[2]+ps[3])) + ((ps[4]+ps[5]) + (ps[6]+ps[7]));
          U8 PB;
          PB.u[0] = pk(ps[0],ps[1]); PB.u[1] = pk(ps[2],ps[3]);
          PB.u[2] = pk(ps[4],ps[5]); PB.u[3] = pk(ps[6],ps[7]);
          U8 VF0, VF1;
          {
            const uint2 a = *(const uint2*)&sVt[col][kb + quad*4];
            const uint2 b = *(const uint2*)&sVt[col][kb + 16 + quad*4];
            VF0.u[0] = a.x; VF0.u[1] = a.y; VF0.u[2] = b.x; VF0.u[3] = b.y;
            const uint2 c = *(const uint2*)&sVt[16 + col][kb + quad*4];
            const uint2 d = *(const uint2*)&sVt[16 + col][kb + 16 + quad*4];
            VF1.u[0] = c.x; VF1.u[1] = c.y; VF1.u[2] = d.x; VF1.u[3] = d.y;
          }
          O[p2][0] = mfma16(VF0.b, PB.b, O[p2][0]);
          O[p2][1] = mfma16(VF1.b, PB.b, O[p2][1]);
        }
      }
      __syncthreads();   // protect sK/sVt before the next half / head overwrites
    }

    // -------- epilogue: normalize, gate, fused out-projection --------
    U8 WoA0, WoA1;   // Wo A-frags with matching k-permutation (qt-invariant)
    {
      const float4 a = *(const float4*)(Wo + col*128 + h*32 + quad*4);
      const float4 b = *(const float4*)(Wo + col*128 + h*32 + 16 + quad*4);
      WoA0.u[0] = pk(a.x,a.y); WoA0.u[1] = pk(a.z,a.w);
      WoA0.u[2] = pk(b.x,b.y); WoA0.u[3] = pk(b.z,b.w);
      const float4 c = *(const float4*)(Wo + (16 + col)*128 + h*32 + quad*4);
      const float4 d = *(const float4*)(Wo + (16 + col)*128 + h*32 + 16 + quad*4);
      WoA1.u[0] = pk(c.x,c.y); WoA1.u[1] = pk(c.z,c.w);
      WoA1.u[2] = pk(d.x,d.y); WoA1.u[3] = pk(d.z,d.w);
    }
#pragma unroll
    for (int p2 = 0; p2 < 2; p2++) {
      float lv = l[p2];
      lv += __shfl_xor(lv, 16);   // reduce over quads (keys spread reg-dim x quad)
      lv += __shfl_xor(lv, 32);
      const float inv = __builtin_amdgcn_rcpf(lv);   // 1 ulp, values O(100)
      float og[8];
#pragma unroll
      for (int r = 0; r < 4; r++) {
        og[r]     = O[p2][0][r] * inv * G[p2][r];
        og[4 + r] = O[p2][1][r] * inv * G[p2][4 + r];
      }
      U8 OB;   // gated O^T as permuted-k B-frag (k-permutation matches WoA)
      OB.u[0] = pk(og[0],og[1]); OB.u[1] = pk(og[2],og[3]);
      OB.u[2] = pk(og[4],og[5]); OB.u[3] = pk(og[6],og[7]);
      acc[p2][0] = mfma16(WoA0.b, OB.b, acc[p2][0]);   // couts 0..15
      acc[p2][1] = mfma16(WoA1.b, OB.b, acc[p2][1]);   // couts 16..31
    }
  }

  // ---------------- epilogue: + bo, float4 stores ----------------
  float bo0[4], bo1[4];
#pragma unroll
  for (int r = 0; r < 4; r++) {
    bo0[r] = bo[quad*4 + r];
    bo1[r] = bo[16 + quad*4 + r];
  }
#pragma unroll
  for (int p2 = 0; p2 < 2; p2++) {
    const int pos = (i << 8) + qhalf*128 + (p2*4 + wave)*16 + col;
    float* op = out + pos*32;
    *(float4*)(op + quad*4)      = make_float4(acc[p2][0][0] + bo0[0], acc[p2][0][1] + bo0[1],
                                               acc[p2][0][2] + bo0[2], acc[p2][0][3] + bo0[3]);
    *(float4*)(op + 16 + quad*4) = make_float4(acc[p2][1][0] + bo1[0], acc[p2][1][1] + bo1[1],
                                               acc[p2][1][2] + bo1[2], acc[p2][1][3] + bo1[3]);
  }
}

extern "C" void kernel_launch(void* const* d_in, const int* in_sizes, int n_in,
                              void* d_out, int out_size, void* d_ws, size_t ws_size,
                              hipStream_t stream)
{
  const float* z    = (const float*)d_in[0];
  const float* ln_g = (const float*)d_in[1];
  const float* ln_b = (const float*)d_in[2];
  const float* Wq   = (const float*)d_in[3];
  const float* Wk   = (const float*)d_in[4];
  const float* Wv   = (const float*)d_in[5];
  // d_in[6] = Wb: softmax shift invariance -> exactly cancels, unused.
  const float* Wg   = (const float*)d_in[7];
  const float* bg   = (const float*)d_in[8];
  const float* Wo   = (const float*)d_in[9];
  const float* bo   = (const float*)d_in[10];

  tri_attn_fused<<<dim3(2, 256), 256, 0, stream>>>(z, ln_g, ln_b, Wq, Wk, Wv, Wg, bg, Wo, bo,
                                                   (float*)d_out);
}